// Round 5
// baseline (28.830 us; speedup 1.0000x reference)
//
#include <hip/hip_runtime.h>
#include <math.h>

// Problem constants
constexpr int B = 32;
constexpr int N = 1024;
constexpr int OCTS = 16;          // row-octets per batch (64 rows each side)
constexpr int NBLK = B * OCTS;    // 512 blocks
constexpr int NTHR = 512;         // 8 waves: 4 pred-strips + 4 gt-strips
constexpr unsigned short ONE_BF = 0x3F80;  // bf16 1.0

typedef __attribute__((ext_vector_type(8))) short short8;
typedef __attribute__((ext_vector_type(4))) float f32x4;

// bf16 hi/lo split: h = bf16_rne(x), l = bf16_rne(x - float(h))
__device__ __forceinline__ void split_bf(float x, unsigned short& h, unsigned short& l) {
    union { float f; unsigned u; } a; a.f = x;
    unsigned r = (a.u + 0x7FFFu + ((a.u >> 16) & 1u)) >> 16;
    h = (unsigned short)r;
    union { unsigned u; float f; } hb; hb.u = r << 16;
    union { float f; unsigned u; } d; d.f = x - hb.f;
    l = (unsigned short)((d.u + 0x7FFFu + ((d.u >> 16) & 1u)) >> 16);
}
// exact -2*h for bf16 bits (sign flip + exponent+1), 0-safe
__device__ __forceinline__ unsigned short neg2bf(unsigned short h) {
    return (unsigned short)((h & 0x7FFFu) ? (unsigned short)((h ^ 0x8000u) + 0x0080u)
                                          : (unsigned short)0);
}
__device__ __forceinline__ unsigned pk(unsigned short a, unsigned short b) {
    return (unsigned)a | ((unsigned)b << 16);
}

// One block per (batch, oct). Waves 0-3: pred rows (dis1); waves 4-7: gt rows (dis2).
// Each wave owns 16 rows, sweeps 64 col-tiles; one MFMA per tile yields the 16x16
// d^2 block directly (norm terms folded into K-slots); 4 fmin/tile running row-min.
// Final reduction fused via threadfence-reduction (last-arriving block).
__global__ __launch_bounds__(NTHR, 4) void chamfer_mfma(
    const float* __restrict__ dR,   // [B,3,3]
    const float* __restrict__ dt,   // [B,3]
    const float* __restrict__ tc,   // [B,3]
    const float* __restrict__ Rc,   // [B,3,3]
    const float* __restrict__ G,    // [B,3,3]
    const float* __restrict__ g,    // [B,3]
    const float* __restrict__ pts,  // [B,N,3]
    const float* __restrict__ sym,  // [B]
    float* __restrict__ partial,    // [NBLK] in d_ws
    unsigned int* __restrict__ counter, // 1 uint in d_ws, zeroed per call
    float* __restrict__ out)        // [1]
{
    __shared__ __align__(16) unsigned short Bp[N][16];   // pred B-form (32B/pt)
    __shared__ __align__(16) unsigned short Bg[N][16];   // gt   B-form
    __shared__ __align__(16) unsigned short Ap[64][32];  // pred A-form (64B/row, hi 32B = 0)
    __shared__ __align__(16) unsigned short Ag[64][32];  // gt   A-form
    __shared__ float wsum[8];
    __shared__ int lastflag;

    const int blk = blockIdx.x;
    const int b   = blk >> 4;
    const int oct = blk & 15;
    const int t   = threadIdx.x;

    // ---- uniform per-block transforms ----
    const float* dRb = dR + b * 9;
    const float* Rcb = Rc + b * 9;
    const float* Gb  = G  + b * 9;
    const float* dtb = dt + b * 3;
    const float* tcb = tc + b * 3;
    const float* gb  = g  + b * 3;
    const float symb = sym[b];

    float M[9], v[3];
    #pragma unroll
    for (int j = 0; j < 3; ++j) {
        #pragma unroll
        for (int i = 0; i < 3; ++i)
            M[j*3+i] = Rcb[j*3+0]*dRb[0*3+i] + Rcb[j*3+1]*dRb[1*3+i] + Rcb[j*3+2]*dRb[2*3+i];
        v[j] = Rcb[j*3+0]*dtb[0] + Rcb[j*3+1]*dtb[1] + Rcb[j*3+2]*dtb[2] + tcb[j];
    }

    float acc = 0.f;

    // ---- stage: 2 points per thread -> pose, split, pack to LDS ----
    {
        const float2* P2 = (const float2*)(pts + (size_t)b * N * 3);
        const float2 u0 = P2[3*t + 0];
        const float2 u1 = P2[3*t + 1];
        const float2 u2 = P2[3*t + 2];
        const float pxs[2] = {u0.x, u1.y};
        const float pys[2] = {u0.y, u2.x};
        const float pzs[2] = {u1.x, u2.y};
        #pragma unroll
        for (int s = 0; s < 2; ++s) {
            const int i = 2*t + s;
            const float px = pxs[s], py = pys[s], pz = pzs[s];
            const float ax = fmaf(M[0],px, fmaf(M[1],py, fmaf(M[2],pz, v[0])));
            const float ay = fmaf(M[3],px, fmaf(M[4],py, fmaf(M[5],pz, v[1])));
            const float az = fmaf(M[6],px, fmaf(M[7],py, fmaf(M[8],pz, v[2])));
            const float cx = fmaf(Gb[0],px, fmaf(Gb[1],py, fmaf(Gb[2],pz, gb[0])));
            const float cy = fmaf(Gb[3],px, fmaf(Gb[4],py, fmaf(Gb[5],pz, gb[1])));
            const float cz = fmaf(Gb[6],px, fmaf(Gb[7],py, fmaf(Gb[8],pz, gb[2])));
            const float a2 = ax*ax + ay*ay + az*az;
            const float c2 = cx*cx + cy*cy + cz*cz;

            if (oct == 0) {  // l2 term exactly once per batch
                const float dx = ax - cx, dy = ay - cy, dz = az - cz;
                acc += (1.f - symb) * sqrtf(dx*dx + dy*dy + dz*dz);
            }

            unsigned short axh,axl, ayh,ayl, azh,azl, anh,anl;
            unsigned short cxh,cxl, cyh,cyl, czh,czl, cnh,cnl;
            split_bf(ax,axh,axl); split_bf(ay,ayh,ayl); split_bf(az,azh,azl); split_bf(a2,anh,anl);
            split_bf(cx,cxh,cxl); split_bf(cy,cyh,cyl); split_bf(cz,czh,czl); split_bf(c2,cnh,cnl);

            // B-forms: [h,h,h, h,h,h, l,l,l, l,l,l, 1,1, n2h,n2l]
            uint4 bp0 = {pk(axh,ayh), pk(azh,axh), pk(ayh,azh), pk(axl,ayl)};
            uint4 bp1 = {pk(azl,axl), pk(ayl,azl), pk(ONE_BF,ONE_BF), pk(anh,anl)};
            *(uint4*)&Bp[i][0] = bp0; *(uint4*)&Bp[i][8] = bp1;
            uint4 bg0 = {pk(cxh,cyh), pk(czh,cxh), pk(cyh,czh), pk(cxl,cyl)};
            uint4 bg1 = {pk(czl,cxl), pk(cyl,czl), pk(ONE_BF,ONE_BF), pk(cnh,cnl)};
            *(uint4*)&Bg[i][0] = bg0; *(uint4*)&Bg[i][8] = bg1;

            // A-forms only for this oct's 64 rows:
            // [-2h(3), -2l(3), -2h(3), -2l(3), n2h,n2l, 1,1] + 16 zero slots
            if ((i >> 6) == oct) {
                const int lr = i & 63;
                const unsigned short nxh=neg2bf(axh), nyh=neg2bf(ayh), nzh=neg2bf(azh);
                const unsigned short nxl=neg2bf(axl), nyl=neg2bf(ayl), nzl=neg2bf(azl);
                uint4 a0 = {pk(nxh,nyh), pk(nzh,nxl), pk(nyl,nzl), pk(nxh,nyh)};
                uint4 a1 = {pk(nzh,nxl), pk(nyl,nzl), pk(anh,anl), pk(ONE_BF,ONE_BF)};
                uint4 zz = {0,0,0,0};
                *(uint4*)&Ap[lr][0] = a0; *(uint4*)&Ap[lr][8]  = a1;
                *(uint4*)&Ap[lr][16] = zz; *(uint4*)&Ap[lr][24] = zz;
                const unsigned short mxh=neg2bf(cxh), myh=neg2bf(cyh), mzh=neg2bf(czh);
                const unsigned short mxl=neg2bf(cxl), myl=neg2bf(cyl), mzl=neg2bf(czl);
                uint4 c0 = {pk(mxh,myh), pk(mzh,mxl), pk(myl,mzl), pk(mxh,myh)};
                uint4 c1 = {pk(mzh,mxl), pk(myl,mzl), pk(cnh,cnl), pk(ONE_BF,ONE_BF)};
                *(uint4*)&Ag[lr][0] = c0; *(uint4*)&Ag[lr][8]  = c1;
                *(uint4*)&Ag[lr][16] = zz; *(uint4*)&Ag[lr][24] = zz;
            }
        }
    }
    __syncthreads();

    // ---- MFMA sweep ----
    const int w    = t >> 6;
    const int lane = t & 63;
    const int side = w >> 2;        // 0: pred rows vs gt cols; 1: gt rows vs pred cols
    const int strip= w & 3;
    const int col  = lane & 15;
    const int kg   = lane >> 4;

    const unsigned short* Abase = (side ? &Ag[0][0] : &Ap[0][0])
                                  + (strip*16 + col) * 32 + kg * 8;
    const unsigned short* Bbase = (side ? &Bp[0][0] : &Bg[0][0])
                                  + col * 16 + (kg & 1) * 8;

    const short8 av = *(const short8*)Abase;
    const f32x4 zero = {0.f, 0.f, 0.f, 0.f};
    float r0 = 3.4e38f, r1 = 3.4e38f, r2 = 3.4e38f, r3 = 3.4e38f;

    #pragma unroll 8
    for (int tile = 0; tile < 64; ++tile) {
        const short8 bv = *(const short8*)(Bbase + tile * 256);
        const f32x4 c = __builtin_amdgcn_mfma_f32_16x16x32_bf16(av, bv, zero, 0, 0, 0);
        r0 = fminf(r0, c[0]); r1 = fminf(r1, c[1]);
        r2 = fminf(r2, c[2]); r3 = fminf(r3, c[3]);
    }

    // reduce row-mins across the 16 col-lanes
    #pragma unroll
    for (int m = 1; m <= 8; m <<= 1) {
        r0 = fminf(r0, __shfl_xor(r0, m));
        r1 = fminf(r1, __shfl_xor(r1, m));
        r2 = fminf(r2, __shfl_xor(r2, m));
        r3 = fminf(r3, __shfl_xor(r3, m));
    }
    if (col == 0) {
        acc += 0.5f * symb * (sqrtf(fmaxf(r0, 0.f)) + sqrtf(fmaxf(r1, 0.f)) +
                              sqrtf(fmaxf(r2, 0.f)) + sqrtf(fmaxf(r3, 0.f)));
    }

    // ---- block sum ----
    #pragma unroll
    for (int m = 1; m <= 32; m <<= 1) acc += __shfl_xor(acc, m);
    if (lane == 0) wsum[w] = acc;
    __syncthreads();
    if (t == 0) {
        float s = 0.f;
        #pragma unroll
        for (int j = 0; j < 8; ++j) s += wsum[j];
        partial[blk] = s;
        __threadfence();                       // release partial to agent scope
        const unsigned old = atomicAdd(counter, 1u);
        lastflag = (old == (unsigned)(NBLK - 1));
    }
    __syncthreads();

    // ---- last-arriving block: final reduction (deterministic fixed order) ----
    if (lastflag) {
        __threadfence();                       // acquire: see all partials
        float a = __hip_atomic_load(&partial[t], __ATOMIC_RELAXED,
                                    __HIP_MEMORY_SCOPE_AGENT);   // NBLK==NTHR==512
        #pragma unroll
        for (int m = 1; m <= 32; m <<= 1) a += __shfl_xor(a, m);
        if (lane == 0) wsum[w] = a;
        __syncthreads();
        if (t == 0) {
            float s = 0.f;
            #pragma unroll
            for (int j = 0; j < 8; ++j) s += wsum[j];
            out[0] = s * (1.0f / (float)(B * N));
        }
    }
}

extern "C" void kernel_launch(void* const* d_in, const int* in_sizes, int n_in,
                              void* d_out, int out_size, void* d_ws, size_t ws_size,
                              hipStream_t stream) {
    const float* dR  = (const float*)d_in[0];
    const float* dt  = (const float*)d_in[1];
    const float* tc  = (const float*)d_in[2];
    const float* Rc  = (const float*)d_in[3];
    const float* G   = (const float*)d_in[4];
    const float* g   = (const float*)d_in[5];
    const float* pts = (const float*)d_in[6];
    const float* sym = (const float*)d_in[7];

    float* partial        = (float*)d_ws;                       // NBLK floats
    unsigned int* counter = (unsigned int*)((char*)d_ws + 4096);
    float* out            = (float*)d_out;

    hipMemsetAsync(counter, 0, sizeof(unsigned int), stream);   // graph-capturable node
    chamfer_mfma<<<NBLK, NTHR, 0, stream>>>(dR, dt, tc, Rc, G, g, pts, sym,
                                            partial, counter, out);
}

// Round 6
// 18.809 us; speedup vs baseline: 1.5328x; 1.5328x over previous
//
#include <hip/hip_runtime.h>
#include <math.h>

// Problem constants
constexpr int B = 32;
constexpr int N = 1024;
constexpr int OCTS = 8;           // row-groups per batch (128 rows each side)
constexpr int NBLK = B * OCTS;    // 256 blocks
constexpr int NTHR = 512;         // 8 waves: 4 pred-strips + 4 gt-strips (32 rows each)
constexpr unsigned short ONE_BF = 0x3F80;  // bf16 1.0

typedef __attribute__((ext_vector_type(8))) short short8;
typedef __attribute__((ext_vector_type(16))) float f32x16;

// bf16 hi/lo split: h = bf16_rne(x), l = bf16_rne(x - float(h))
__device__ __forceinline__ void split_bf(float x, unsigned short& h, unsigned short& l) {
    union { float f; unsigned u; } a; a.f = x;
    unsigned r = (a.u + 0x7FFFu + ((a.u >> 16) & 1u)) >> 16;
    h = (unsigned short)r;
    union { unsigned u; float f; } hb; hb.u = r << 16;
    union { float f; unsigned u; } d; d.f = x - hb.f;
    l = (unsigned short)((d.u + 0x7FFFu + ((d.u >> 16) & 1u)) >> 16);
}
// exact -2*h for bf16 bits (sign flip + exponent+1), 0-safe
__device__ __forceinline__ unsigned short neg2bf(unsigned short h) {
    return (unsigned short)((h & 0x7FFFu) ? (unsigned short)((h ^ 0x8000u) + 0x0080u)
                                          : (unsigned short)0);
}
__device__ __forceinline__ unsigned pk(unsigned short a, unsigned short b) {
    return (unsigned)a | ((unsigned)b << 16);
}

// One block per (batch, oct of 128 rows). Waves 0-3: pred rows (dis1);
// waves 4-7: gt rows (dis2). Each wave owns 32 rows, sweeps 32 col-tiles of 32;
// ONE mfma_32x32x16 per tile yields the full 32x32 d^2 block (norm terms folded
// into the 16 K-slots). B stored tile-major [tile][kg][col][8]: inner-loop
// ds_read_b128 = 64 lanes reading 1024 consecutive bytes (conflict-free,
// offset-immediate addressing).
__global__ __launch_bounds__(NTHR, 4) void chamfer_mfma(
    const float* __restrict__ dR,   // [B,3,3]
    const float* __restrict__ dt,   // [B,3]
    const float* __restrict__ tc,   // [B,3]
    const float* __restrict__ Rc,   // [B,3,3]
    const float* __restrict__ G,    // [B,3,3]
    const float* __restrict__ g,    // [B,3]
    const float* __restrict__ pts,  // [B,N,3]
    const float* __restrict__ sym,  // [B]
    float* __restrict__ partial)    // [NBLK]
{
    // B-forms, tile-major interleaved: [tile][kg][col][8 shorts] = 32 KB each
    __shared__ __align__(16) unsigned short BpT[32][2][32][8];
    __shared__ __align__(16) unsigned short BgT[32][2][32][8];
    // A-forms for this block's 128 rows per side: [row][16 shorts] = 4 KB each
    __shared__ __align__(16) unsigned short Ap[128][16];
    __shared__ __align__(16) unsigned short Ag[128][16];
    __shared__ float wsum[8];

    const int blk = blockIdx.x;
    const int b   = blk >> 3;
    const int oct = blk & 7;
    const int t   = threadIdx.x;

    // ---- uniform per-block transforms ----
    const float* dRb = dR + b * 9;
    const float* Rcb = Rc + b * 9;
    const float* Gb  = G  + b * 9;
    const float* dtb = dt + b * 3;
    const float* tcb = tc + b * 3;
    const float* gb  = g  + b * 3;
    const float symb = sym[b];

    float M[9], v[3];
    #pragma unroll
    for (int j = 0; j < 3; ++j) {
        #pragma unroll
        for (int i = 0; i < 3; ++i)
            M[j*3+i] = Rcb[j*3+0]*dRb[0*3+i] + Rcb[j*3+1]*dRb[1*3+i] + Rcb[j*3+2]*dRb[2*3+i];
        v[j] = Rcb[j*3+0]*dtb[0] + Rcb[j*3+1]*dtb[1] + Rcb[j*3+2]*dtb[2] + tcb[j];
    }

    float acc = 0.f;

    // ---- stage: 2 points per thread -> pose, split, pack to LDS ----
    {
        const float2* P2 = (const float2*)(pts + (size_t)b * N * 3);
        const float2 u0 = P2[3*t + 0];
        const float2 u1 = P2[3*t + 1];
        const float2 u2 = P2[3*t + 2];
        const float pxs[2] = {u0.x, u1.y};
        const float pys[2] = {u0.y, u2.x};
        const float pzs[2] = {u1.x, u2.y};
        #pragma unroll
        for (int s = 0; s < 2; ++s) {
            const int i = 2*t + s;
            const float px = pxs[s], py = pys[s], pz = pzs[s];
            const float ax = fmaf(M[0],px, fmaf(M[1],py, fmaf(M[2],pz, v[0])));
            const float ay = fmaf(M[3],px, fmaf(M[4],py, fmaf(M[5],pz, v[1])));
            const float az = fmaf(M[6],px, fmaf(M[7],py, fmaf(M[8],pz, v[2])));
            const float cx = fmaf(Gb[0],px, fmaf(Gb[1],py, fmaf(Gb[2],pz, gb[0])));
            const float cy = fmaf(Gb[3],px, fmaf(Gb[4],py, fmaf(Gb[5],pz, gb[1])));
            const float cz = fmaf(Gb[6],px, fmaf(Gb[7],py, fmaf(Gb[8],pz, gb[2])));
            const float a2 = ax*ax + ay*ay + az*az;
            const float c2 = cx*cx + cy*cy + cz*cz;

            if (oct == 0) {  // l2 term exactly once per batch
                const float dx = ax - cx, dy = ay - cy, dz = az - cz;
                acc += (1.f - symb) * sqrtf(dx*dx + dy*dy + dz*dz);
            }

            unsigned short axh,axl, ayh,ayl, azh,azl, anh,anl;
            unsigned short cxh,cxl, cyh,cyl, czh,czl, cnh,cnl;
            split_bf(ax,axh,axl); split_bf(ay,ayh,ayl); split_bf(az,azh,azl); split_bf(a2,anh,anl);
            split_bf(cx,cxh,cxl); split_bf(cy,cyh,cyl); split_bf(cz,czh,czl); split_bf(c2,cnh,cnl);

            // B-form K-slots: [h,h,h, h,h,h, l,l,l, l,l,l, 1,1, n2h,n2l]
            const int tile = i >> 5, c = i & 31;
            uint4 bp0 = {pk(axh,ayh), pk(azh,axh), pk(ayh,azh), pk(axl,ayl)};
            uint4 bp1 = {pk(azl,axl), pk(ayl,azl), pk(ONE_BF,ONE_BF), pk(anh,anl)};
            *(uint4*)&BpT[tile][0][c][0] = bp0;
            *(uint4*)&BpT[tile][1][c][0] = bp1;
            uint4 bg0 = {pk(cxh,cyh), pk(czh,cxh), pk(cyh,czh), pk(cxl,cyl)};
            uint4 bg1 = {pk(czl,cxl), pk(cyl,czl), pk(ONE_BF,ONE_BF), pk(cnh,cnl)};
            *(uint4*)&BgT[tile][0][c][0] = bg0;
            *(uint4*)&BgT[tile][1][c][0] = bg1;

            // A-form K-slots for this block's 128 rows:
            // [-2h(3), -2l(3), -2h(3), -2l(3), n2h,n2l, 1,1]
            if ((i >> 7) == oct) {
                const int lr = i & 127;
                const unsigned short nxh=neg2bf(axh), nyh=neg2bf(ayh), nzh=neg2bf(azh);
                const unsigned short nxl=neg2bf(axl), nyl=neg2bf(ayl), nzl=neg2bf(azl);
                uint4 a0 = {pk(nxh,nyh), pk(nzh,nxl), pk(nyl,nzl), pk(nxh,nyh)};
                uint4 a1 = {pk(nzh,nxl), pk(nyl,nzl), pk(anh,anl), pk(ONE_BF,ONE_BF)};
                *(uint4*)&Ap[lr][0] = a0; *(uint4*)&Ap[lr][8] = a1;
                const unsigned short mxh=neg2bf(cxh), myh=neg2bf(cyh), mzh=neg2bf(czh);
                const unsigned short mxl=neg2bf(cxl), myl=neg2bf(cyl), mzl=neg2bf(czl);
                uint4 c0 = {pk(mxh,myh), pk(mzh,mxl), pk(myl,mzl), pk(mxh,myh)};
                uint4 c1 = {pk(mzh,mxl), pk(myl,mzl), pk(cnh,cnl), pk(ONE_BF,ONE_BF)};
                *(uint4*)&Ag[lr][0] = c0; *(uint4*)&Ag[lr][8] = c1;
            }
        }
    }
    __syncthreads();

    // ---- MFMA sweep: each wave = 32 rows vs all 1024 cols ----
    const int w    = t >> 6;
    const int lane = t & 63;
    const int side = w >> 2;        // 0: pred rows vs gt cols; 1: gt rows vs pred cols
    const int strip= w & 3;
    const int c32  = lane & 31;
    const int kg   = lane >> 5;

    // A fragment (hoisted): row = strip*32 + c32, k-half = kg
    const unsigned short* Aside = side ? &Ag[0][0] : &Ap[0][0];
    const short8 av = *(const short8*)(Aside + (strip*32 + c32) * 16 + kg * 8);

    // B base: tile-major; lane's 16B slot = lane*16 bytes within each 1KB tile
    const short8* Bside = (const short8*)(side ? &BpT[0][0][0][0] : &BgT[0][0][0][0]);
    const short8* Bl = Bside + lane;

    f32x16 mins;
    #pragma unroll
    for (int i = 0; i < 16; ++i) mins[i] = 3.4e38f;

    #pragma unroll 8
    for (int tile = 0; tile < 32; ++tile) {
        const short8 bv = Bl[tile * 64];    // ds_read_b128, offset tile*1024
        const f32x16 c = __builtin_amdgcn_mfma_f32_32x32x16_bf16(av, bv, mins*0.f, 0, 0, 0);
        #pragma unroll
        for (int i = 0; i < 16; ++i) mins[i] = fminf(mins[i], c[i]);
    }

    // ---- reduce row-mins across the 32 col-lanes (C: col=lane&31) ----
    #pragma unroll
    for (int i = 0; i < 16; ++i) {
        float m = mins[i];
        #pragma unroll
        for (int mm = 1; mm <= 16; mm <<= 1)
            m = fminf(m, __shfl_xor(m, mm));
        mins[i] = m;
    }
    // lanes 0 and 32 hold the 32 row-mins (rows (i&3)+8*(i>>2)+4*(lane>>5))
    if (c32 == 0) {
        float s = 0.f;
        #pragma unroll
        for (int i = 0; i < 16; ++i) s += sqrtf(fmaxf(mins[i], 0.f));
        acc += 0.5f * symb * s;
    }

    // ---- block sum ----
    #pragma unroll
    for (int m = 1; m <= 32; m <<= 1) acc += __shfl_xor(acc, m);
    if (lane == 0) wsum[w] = acc;
    __syncthreads();
    if (t == 0) {
        float s = 0.f;
        #pragma unroll
        for (int j = 0; j < 8; ++j) s += wsum[j];
        partial[blk] = s;
    }
}

// Final reduction: 256 partials -> scalar mean (single wave)
__global__ __launch_bounds__(64) void chamfer_final(
    const float* __restrict__ partial, float* __restrict__ out)
{
    const int t = threadIdx.x;
    const float4 v = ((const float4*)partial)[t];   // 64*4 = 256
    float a = (v.x + v.y) + (v.z + v.w);
    #pragma unroll
    for (int m = 1; m <= 32; m <<= 1) a += __shfl_xor(a, m);
    if (t == 0) out[0] = a * (1.0f / (float)(B * N));
}

extern "C" void kernel_launch(void* const* d_in, const int* in_sizes, int n_in,
                              void* d_out, int out_size, void* d_ws, size_t ws_size,
                              hipStream_t stream) {
    const float* dR  = (const float*)d_in[0];
    const float* dt  = (const float*)d_in[1];
    const float* tc  = (const float*)d_in[2];
    const float* Rc  = (const float*)d_in[3];
    const float* G   = (const float*)d_in[4];
    const float* g   = (const float*)d_in[5];
    const float* pts = (const float*)d_in[6];
    const float* sym = (const float*)d_in[7];

    float* partial = (float*)d_ws;     // NBLK floats
    float* out     = (float*)d_out;

    chamfer_mfma<<<NBLK, NTHR, 0, stream>>>(dR, dt, tc, Rc, G, g, pts, sym, partial);
    chamfer_final<<<1, 64, 0, stream>>>(partial, out);
}

// Round 7
// 14.329 us; speedup vs baseline: 2.0120x; 1.3127x over previous
//
#include <hip/hip_runtime.h>
#include <math.h>

// Problem constants
constexpr int B = 32;
constexpr int N = 1024;
constexpr int OCTS = 8;           // row-groups per batch (128 rows each side)
constexpr int NBLK = B * OCTS;    // 256 blocks
constexpr int NTHR = 512;         // 8 waves: 4 pred-strips + 4 gt-strips (32 rows each)
constexpr unsigned short ONE_BF = 0x3F80;  // bf16 1.0

typedef __attribute__((ext_vector_type(8))) short short8;
typedef __attribute__((ext_vector_type(16))) float f32x16;

// bf16 hi/lo split: h = bf16_rne(x), l = bf16_rne(x - float(h))
__device__ __forceinline__ void split_bf(float x, unsigned short& h, unsigned short& l) {
    union { float f; unsigned u; } a; a.f = x;
    unsigned r = (a.u + 0x7FFFu + ((a.u >> 16) & 1u)) >> 16;
    h = (unsigned short)r;
    union { unsigned u; float f; } hb; hb.u = r << 16;
    union { float f; unsigned u; } d; d.f = x - hb.f;
    l = (unsigned short)((d.u + 0x7FFFu + ((d.u >> 16) & 1u)) >> 16);
}
// exact -2*h for bf16 bits (sign flip + exponent+1), 0-safe
__device__ __forceinline__ unsigned short neg2bf(unsigned short h) {
    return (unsigned short)((h & 0x7FFFu) ? (unsigned short)((h ^ 0x8000u) + 0x0080u)
                                          : (unsigned short)0);
}
__device__ __forceinline__ unsigned pk(unsigned short a, unsigned short b) {
    return (unsigned)a | ((unsigned)b << 16);
}

// One block per (batch, oct of 128 rows). Waves 0-3: pred rows (dis1);
// waves 4-7: gt rows (dis2). Each wave owns 32 rows, sweeps 32 col-tiles of 32;
// ONE mfma_32x32x16 per tile yields the full 32x32 d^2 block (norm terms folded
// into the 16 K-slots). C operand is a CONSTANT zero vector: MFMAs are mutually
// independent and pipeline; the fmin chain hangs off the results. (R6's
// mins*0.f serialized the MFMAs -> 3.6us regression.)
__global__ __launch_bounds__(NTHR, 4) void chamfer_mfma(
    const float* __restrict__ dR,   // [B,3,3]
    const float* __restrict__ dt,   // [B,3]
    const float* __restrict__ tc,   // [B,3]
    const float* __restrict__ Rc,   // [B,3,3]
    const float* __restrict__ G,    // [B,3,3]
    const float* __restrict__ g,    // [B,3]
    const float* __restrict__ pts,  // [B,N,3]
    const float* __restrict__ sym,  // [B]
    float* __restrict__ partial)    // [NBLK]
{
    // B-forms, tile-major interleaved: [tile][kg][col][8 shorts] = 32 KB each
    __shared__ __align__(16) unsigned short BpT[32][2][32][8];
    __shared__ __align__(16) unsigned short BgT[32][2][32][8];
    // A-forms for this block's 128 rows per side: [row][16 shorts] = 4 KB each
    __shared__ __align__(16) unsigned short Ap[128][16];
    __shared__ __align__(16) unsigned short Ag[128][16];
    __shared__ float wsum[8];

    const int blk = blockIdx.x;
    const int b   = blk >> 3;
    const int oct = blk & 7;
    const int t   = threadIdx.x;

    // ---- uniform per-block transforms ----
    const float* dRb = dR + b * 9;
    const float* Rcb = Rc + b * 9;
    const float* Gb  = G  + b * 9;
    const float* dtb = dt + b * 3;
    const float* tcb = tc + b * 3;
    const float* gb  = g  + b * 3;
    const float symb = sym[b];

    float M[9], v[3];
    #pragma unroll
    for (int j = 0; j < 3; ++j) {
        #pragma unroll
        for (int i = 0; i < 3; ++i)
            M[j*3+i] = Rcb[j*3+0]*dRb[0*3+i] + Rcb[j*3+1]*dRb[1*3+i] + Rcb[j*3+2]*dRb[2*3+i];
        v[j] = Rcb[j*3+0]*dtb[0] + Rcb[j*3+1]*dtb[1] + Rcb[j*3+2]*dtb[2] + tcb[j];
    }

    float acc = 0.f;

    // ---- stage: 2 points per thread -> pose, split, pack to LDS ----
    {
        const float2* P2 = (const float2*)(pts + (size_t)b * N * 3);
        const float2 u0 = P2[3*t + 0];
        const float2 u1 = P2[3*t + 1];
        const float2 u2 = P2[3*t + 2];
        const float pxs[2] = {u0.x, u1.y};
        const float pys[2] = {u0.y, u2.x};
        const float pzs[2] = {u1.x, u2.y};
        #pragma unroll
        for (int s = 0; s < 2; ++s) {
            const int i = 2*t + s;
            const float px = pxs[s], py = pys[s], pz = pzs[s];
            const float ax = fmaf(M[0],px, fmaf(M[1],py, fmaf(M[2],pz, v[0])));
            const float ay = fmaf(M[3],px, fmaf(M[4],py, fmaf(M[5],pz, v[1])));
            const float az = fmaf(M[6],px, fmaf(M[7],py, fmaf(M[8],pz, v[2])));
            const float cx = fmaf(Gb[0],px, fmaf(Gb[1],py, fmaf(Gb[2],pz, gb[0])));
            const float cy = fmaf(Gb[3],px, fmaf(Gb[4],py, fmaf(Gb[5],pz, gb[1])));
            const float cz = fmaf(Gb[6],px, fmaf(Gb[7],py, fmaf(Gb[8],pz, gb[2])));
            const float a2 = ax*ax + ay*ay + az*az;
            const float c2 = cx*cx + cy*cy + cz*cz;

            if (oct == 0) {  // l2 term exactly once per batch
                const float dx = ax - cx, dy = ay - cy, dz = az - cz;
                acc += (1.f - symb) * sqrtf(dx*dx + dy*dy + dz*dz);
            }

            unsigned short axh,axl, ayh,ayl, azh,azl, anh,anl;
            unsigned short cxh,cxl, cyh,cyl, czh,czl, cnh,cnl;
            split_bf(ax,axh,axl); split_bf(ay,ayh,ayl); split_bf(az,azh,azl); split_bf(a2,anh,anl);
            split_bf(cx,cxh,cxl); split_bf(cy,cyh,cyl); split_bf(cz,czh,czl); split_bf(c2,cnh,cnl);

            // B-form K-slots: [h,h,h, h,h,h, l,l,l, l,l,l, 1,1, n2h,n2l]
            const int tile = i >> 5, c = i & 31;
            uint4 bp0 = {pk(axh,ayh), pk(azh,axh), pk(ayh,azh), pk(axl,ayl)};
            uint4 bp1 = {pk(azl,axl), pk(ayl,azl), pk(ONE_BF,ONE_BF), pk(anh,anl)};
            *(uint4*)&BpT[tile][0][c][0] = bp0;
            *(uint4*)&BpT[tile][1][c][0] = bp1;
            uint4 bg0 = {pk(cxh,cyh), pk(czh,cxh), pk(cyh,czh), pk(cxl,cyl)};
            uint4 bg1 = {pk(czl,cxl), pk(cyl,czl), pk(ONE_BF,ONE_BF), pk(cnh,cnl)};
            *(uint4*)&BgT[tile][0][c][0] = bg0;
            *(uint4*)&BgT[tile][1][c][0] = bg1;

            // A-form K-slots for this block's 128 rows:
            // [-2h(3), -2l(3), -2h(3), -2l(3), n2h,n2l, 1,1]
            if ((i >> 7) == oct) {
                const int lr = i & 127;
                const unsigned short nxh=neg2bf(axh), nyh=neg2bf(ayh), nzh=neg2bf(azh);
                const unsigned short nxl=neg2bf(axl), nyl=neg2bf(ayl), nzl=neg2bf(azl);
                uint4 a0 = {pk(nxh,nyh), pk(nzh,nxl), pk(nyl,nzl), pk(nxh,nyh)};
                uint4 a1 = {pk(nzh,nxl), pk(nyl,nzl), pk(anh,anl), pk(ONE_BF,ONE_BF)};
                *(uint4*)&Ap[lr][0] = a0; *(uint4*)&Ap[lr][8] = a1;
                const unsigned short mxh=neg2bf(cxh), myh=neg2bf(cyh), mzh=neg2bf(czh);
                const unsigned short mxl=neg2bf(cxl), myl=neg2bf(cyl), mzl=neg2bf(czl);
                uint4 c0 = {pk(mxh,myh), pk(mzh,mxl), pk(myl,mzl), pk(mxh,myh)};
                uint4 c1 = {pk(mzh,mxl), pk(myl,mzl), pk(cnh,cnl), pk(ONE_BF,ONE_BF)};
                *(uint4*)&Ag[lr][0] = c0; *(uint4*)&Ag[lr][8] = c1;
            }
        }
    }
    __syncthreads();

    // ---- MFMA sweep: each wave = 32 rows vs all 1024 cols ----
    const int w    = t >> 6;
    const int lane = t & 63;
    const int side = w >> 2;        // 0: pred rows vs gt cols; 1: gt rows vs pred cols
    const int strip= w & 3;
    const int c32  = lane & 31;
    const int kg   = lane >> 5;

    // A fragment (hoisted): row = strip*32 + c32, k-half = kg
    const unsigned short* Aside = side ? &Ag[0][0] : &Ap[0][0];
    const short8 av = *(const short8*)(Aside + (strip*32 + c32) * 16 + kg * 8);

    // B base: tile-major; lane's 16B slot = lane*16 bytes within each 1KB tile
    const short8* Bside = (const short8*)(side ? &BpT[0][0][0][0] : &BgT[0][0][0][0]);
    const short8* Bl = Bside + lane;

    const f32x16 czero = {0.f,0.f,0.f,0.f, 0.f,0.f,0.f,0.f,
                          0.f,0.f,0.f,0.f, 0.f,0.f,0.f,0.f};
    f32x16 mins;
    #pragma unroll
    for (int i = 0; i < 16; ++i) mins[i] = 3.4e38f;

    #pragma unroll 8
    for (int tile = 0; tile < 32; ++tile) {
        const short8 bv = Bl[tile * 64];    // ds_read_b128, offset tile*1024
        const f32x16 c = __builtin_amdgcn_mfma_f32_32x32x16_bf16(av, bv, czero, 0, 0, 0);
        #pragma unroll
        for (int i = 0; i < 16; ++i) mins[i] = fminf(mins[i], c[i]);
    }

    // ---- reduce row-mins across the 32 col-lanes (C: col=lane&31) ----
    #pragma unroll
    for (int i = 0; i < 16; ++i) {
        float m = mins[i];
        #pragma unroll
        for (int mm = 1; mm <= 16; mm <<= 1)
            m = fminf(m, __shfl_xor(m, mm));
        mins[i] = m;
    }
    // lanes 0 and 32 hold the 32 row-mins (rows (i&3)+8*(i>>2)+4*(lane>>5))
    if (c32 == 0) {
        float s = 0.f;
        #pragma unroll
        for (int i = 0; i < 16; ++i) s += sqrtf(fmaxf(mins[i], 0.f));
        acc += 0.5f * symb * s;
    }

    // ---- block sum ----
    #pragma unroll
    for (int m = 1; m <= 32; m <<= 1) acc += __shfl_xor(acc, m);
    if (lane == 0) wsum[w] = acc;
    __syncthreads();
    if (t == 0) {
        float s = 0.f;
        #pragma unroll
        for (int j = 0; j < 8; ++j) s += wsum[j];
        partial[blk] = s;
    }
}

// Final reduction: 256 partials -> scalar mean (single wave)
__global__ __launch_bounds__(64) void chamfer_final(
    const float* __restrict__ partial, float* __restrict__ out)
{
    const int t = threadIdx.x;
    const float4 v = ((const float4*)partial)[t];   // 64*4 = 256
    float a = (v.x + v.y) + (v.z + v.w);
    #pragma unroll
    for (int m = 1; m <= 32; m <<= 1) a += __shfl_xor(a, m);
    if (t == 0) out[0] = a * (1.0f / (float)(B * N));
}

extern "C" void kernel_launch(void* const* d_in, const int* in_sizes, int n_in,
                              void* d_out, int out_size, void* d_ws, size_t ws_size,
                              hipStream_t stream) {
    const float* dR  = (const float*)d_in[0];
    const float* dt  = (const float*)d_in[1];
    const float* tc  = (const float*)d_in[2];
    const float* Rc  = (const float*)d_in[3];
    const float* G   = (const float*)d_in[4];
    const float* g   = (const float*)d_in[5];
    const float* pts = (const float*)d_in[6];
    const float* sym = (const float*)d_in[7];

    float* partial = (float*)d_ws;     // NBLK floats
    float* out     = (float*)d_out;

    chamfer_mfma<<<NBLK, NTHR, 0, stream>>>(dR, dt, tc, Rc, G, g, pts, sym, partial);
    chamfer_final<<<1, 64, 0, stream>>>(partial, out);
}